// Round 6
// baseline (63.794 us; speedup 1.0000x reference)
//
#include <hip/hip_runtime.h>

// Fused UDTCWT: 8 levels, phi chain in padded LDS.
// D=1 (lvl1): quad-per-thread. D in {2,4,8}: contiguous-32 block scheme
// (coalesced float4 psi stores, stride-D register-shared loads).
// D>=16: polyphase W=9 (stores have runs >= 64B, lanes consecutive).
// LDS layout padded: phys(p) = p + (p>>5)  -> conflict-free for all phases.
// B=4, C=8 -> 16 chains, T=65536. Output: yl [4][8][T], yh [8][4][16][T].

static constexpr int B   = 4;
static constexpr int C2  = 16;
static constexpr int T   = 65536;
static constexpr int TS  = 4096;
static constexpr int HB  = 1152;
static constexpr int S   = TS + 2 * HB;   // 6400 logical floats
static constexpr int SP  = S + S / 32;    // 6600 padded floats (25.8 KB)
static constexpr int NT  = 256;

__device__ __forceinline__ int PH(int p) { return p + (p >> 5); }

// Margin chain: lvl1 out 1148; each dilated level consumes 4.5*D:
// 1136(D2) 1116(D4) 1080(D8) 1008(D16) 864(D32) 576(D64) 0(D128).

// ---------- D in {2,4,8}: contiguous 32-output blocks ----------
template <int D, int MO>
__device__ __forceinline__ void lvl_block(
    const float* __restrict__ in, float* __restrict__ out,
    const float (&f0)[10], const float (&f1)[10],
    float* __restrict__ psi_g, int gbase, int tid)
{
    constexpr int L     = 32;
    constexpr int WC    = L / D;
    constexpr int HALF  = 9 * D / 2;
    constexpr int START = HB - MO;
    constexpr int END   = HB + TS + MO;
    constexpr int N     = END - START;
    constexpr int NB    = (N + L - 1) / L;

    for (int i = tid; i < NB; i += NT) {
        int p0 = START + L * i;
        if (p0 > END - L) p0 = END - L;            // clamp (dup work, benign)
        const bool core = (p0 + L > HB) && (p0 < HB + TS);

        float av[L], bv[L];
#pragma unroll
        for (int c = 0; c < D; ++c) {
            float v[WC + 9];
            const int base = p0 + c - HALF;
#pragma unroll
            for (int n = 0; n < WC + 9; ++n) v[n] = in[PH(base + n * D)];
            if (core) {
#pragma unroll
                for (int m = 0; m < WC; ++m) {
                    float sa = 0.f, sb = 0.f;
#pragma unroll
                    for (int k = 0; k < 10; ++k) {
                        float xx = v[m + k];
                        sa += xx * f0[k];
                        sb += xx * f1[k];
                    }
                    av[c + m * D] = sa; bv[c + m * D] = sb;
                }
            } else {
#pragma unroll
                for (int m = 0; m < WC; ++m) {
                    float sa = 0.f;
#pragma unroll
                    for (int k = 0; k < 10; ++k) sa += v[m + k] * f0[k];
                    av[c + m * D] = sa;
                }
            }
        }

        if (core) {
#pragma unroll
            for (int t = 0; t < L / 4; ++t) {
                int p = p0 + 4 * t;                 // %4==0 always
                if ((unsigned)(p - HB) < (unsigned)TS)
                    *(float4*)&psi_g[gbase + p] =
                        make_float4(bv[4*t], bv[4*t+1], bv[4*t+2], bv[4*t+3]);
            }
        }
        const int gg0 = gbase + p0;
#pragma unroll
        for (int j = 0; j < L; ++j)
            out[PH(p0 + j)] = ((unsigned)(gg0 + j) < (unsigned)T) ? av[j] : 0.f;
    }
}

// ---------- D >= 16: polyphase W=9 ----------
template <int D, int MO, bool LAST>
__device__ __forceinline__ void lvl_poly(
    const float* __restrict__ in, float* __restrict__ out,
    const float (&f0)[10], const float (&f1)[10],
    float* __restrict__ psi_g, float* __restrict__ yl_g,
    int gbase, int tid, bool wr_yl)
{
    constexpr int W     = 9;
    constexpr int HALF  = 9 * D / 2;
    constexpr int START = HB - MO;
    constexpr int END   = HB + TS + MO;
    constexpr int N     = END - START;
    static_assert(N % D == 0, "");
    constexpr int NPD   = N / D;
    constexpr int CPC   = (NPD + W - 1) / W;
    constexpr int G     = D * CPC;
    constexpr int LOG2D = (D == 16 ? 4 : D == 32 ? 5 : D == 64 ? 6 : 7);

    for (int g = tid; g < G; g += NT) {
        int r = g & (D - 1);
        int q = g >> LOG2D;
        int mstart = q * W;
        if (mstart > NPD - W) mstart = NPD - W;
        int p0 = START + r + mstart * D;

        const int base = p0 - HALF;
        float v[W + 9];
#pragma unroll
        for (int n = 0; n < W + 9; ++n) v[n] = in[PH(base + n * D)];

        if constexpr (!LAST) {
            const bool anyc = (p0 + (W - 1) * D >= HB) && (p0 < HB + TS);
            float a[W], bb[W];
            if (anyc) {
#pragma unroll
                for (int m = 0; m < W; ++m) { a[m] = 0.f; bb[m] = 0.f; }
#pragma unroll
                for (int k = 0; k < 10; ++k)
#pragma unroll
                    for (int m = 0; m < W; ++m) {
                        float xx = v[m + k];
                        a[m] += xx * f0[k]; bb[m] += xx * f1[k];
                    }
#pragma unroll
                for (int m = 0; m < W; ++m) {
                    int p = p0 + m * D;
                    if ((unsigned)(p - HB) < (unsigned)TS)
                        psi_g[gbase + p] = bb[m];
                }
            } else {
#pragma unroll
                for (int m = 0; m < W; ++m) a[m] = 0.f;
#pragma unroll
                for (int k = 0; k < 10; ++k)
#pragma unroll
                    for (int m = 0; m < W; ++m) a[m] += v[m + k] * f0[k];
            }
#pragma unroll
            for (int m = 0; m < W; ++m) {
                int p = p0 + m * D;
                out[PH(p)] = ((unsigned)(gbase + p) < (unsigned)T) ? a[m] : 0.f;
            }
        } else {
            float bb[W];
#pragma unroll
            for (int m = 0; m < W; ++m) bb[m] = 0.f;
#pragma unroll
            for (int k = 0; k < 10; ++k)
#pragma unroll
                for (int m = 0; m < W; ++m) bb[m] += v[m + k] * f1[k];
#pragma unroll
            for (int m = 0; m < W; ++m) psi_g[gbase + p0 + m * D] = bb[m];
            if (wr_yl) {
                float a[W];
#pragma unroll
                for (int m = 0; m < W; ++m) a[m] = 0.f;
#pragma unroll
                for (int k = 0; k < 10; ++k)
#pragma unroll
                    for (int m = 0; m < W; ++m) a[m] += v[m + k] * f0[k];
#pragma unroll
                for (int m = 0; m < W; ++m) yl_g[gbase + p0 + m * D] = a[m];
            }
        }
    }
}

// ---------- Level 1 (D=1): 5-tap phi, 7-tap psi ----------
template <int SH>
__device__ __forceinline__ void lvl1_pass(
    const float* __restrict__ in, float* __restrict__ out,
    const float* __restrict__ h0o, const float* __restrict__ h1o,
    float* __restrict__ psi_g, int gbase, int tid)
{
    float f0[5], f1[7];
#pragma unroll
    for (int k = 0; k < 5; ++k) f0[k] = h0o[k];
#pragma unroll
    for (int k = 0; k < 7; ++k) f1[k] = h1o[k];

    constexpr int WO    = SH ? -3 : -2;
    constexpr int FS    = SH ? 2 : 0;
    constexpr int MO    = 1148;
    constexpr int START = HB - MO;       // 4
    constexpr int END   = HB + TS + MO;  // 6396

    for (int p4 = START + tid * 4; p4 < END; p4 += NT * 4) {
        float w[10];
#pragma unroll
        for (int k = 0; k < 10; ++k) w[k] = in[PH(p4 + WO + k)];
        float a[4];
#pragma unroll
        for (int i = 0; i < 4; ++i) {
            float s = 0.f;
#pragma unroll
            for (int k = 0; k < 5; ++k) s += w[i + k + FS] * f0[k];
            a[i] = s;
        }
        if ((unsigned)(p4 - HB) < (unsigned)TS) {
            float bb[4];
#pragma unroll
            for (int i = 0; i < 4; ++i) {
                float s = 0.f;
#pragma unroll
                for (int k = 0; k < 7; ++k) s += w[i + k] * f1[k];
                bb[i] = s;
            }
            *(float4*)&psi_g[gbase + p4] = make_float4(bb[0], bb[1], bb[2], bb[3]);
        }
        const int gg = gbase + p4;       // quad fully in or out of [0,T)
        const bool inT = (unsigned)gg < (unsigned)T;
#pragma unroll
        for (int i = 0; i < 4; ++i) out[PH(p4 + i)] = inT ? a[i] : 0.f;
    }
}

__global__ __launch_bounds__(256, 3) void udtcwt_fused(
    const float* __restrict__ x,
    const float* __restrict__ h0o, const float* __restrict__ h1o,
    const float* __restrict__ h0a, const float* __restrict__ h1a,
    const float* __restrict__ h0b, const float* __restrict__ h1b,
    float* __restrict__ out)
{
    __shared__ float bufA[SP];
    __shared__ float bufB[SP];

    const int tid   = threadIdx.x;
    const int bid   = blockIdx.x;
    const int tile  = bid & 15;
    const int chain = bid >> 4;
    const int shbit = chain & 1;
    const int cx    = (chain >> 1) & 7;
    const int b     = chain >> 4;
    const int c2    = shbit * 8 + cx;
    const int gbase = tile * TS - HB;    // %4 == 0

    // stage x tile + halo (zeros outside [0,T)); float4 global, scalar LDS
    const float* xin = x + (size_t)(b * 8 + cx) * T;
    for (int i4 = tid * 4; i4 < S; i4 += NT * 4) {
        int gg = gbase + i4;
        float4 val = ((unsigned)gg < (unsigned)T)
                   ? *(const float4*)&xin[gg]
                   : make_float4(0.f, 0.f, 0.f, 0.f);
        int ph = PH(i4);                 // quad contiguous (pads at 32-bnds)
        bufA[ph] = val.x; bufA[ph+1] = val.y; bufA[ph+2] = val.z; bufA[ph+3] = val.w;
    }

    float f0[10], f1[10];
    {
        const float* F0 = (c2 & 1) ? h0b : h0a;
        const float* F1 = (c2 & 1) ? h1b : h1a;
#pragma unroll
        for (int k = 0; k < 10; ++k) { f0[k] = F0[k]; f1[k] = F1[k]; }
    }

    float* yl_g = out + (size_t)(b * 8 + c2) * T;
    float* yh   = out + (size_t)B * 8 * T;
    const size_t LS = (size_t)B * C2 * T;
    float* psi0 = yh + (size_t)(b * C2 + c2) * T;
    const bool wr_yl = (c2 < 8);

    __syncthreads();
    if (shbit) lvl1_pass<1>(bufA, bufB, h0o, h1o, psi0, gbase, tid);
    else       lvl1_pass<0>(bufA, bufB, h0o, h1o, psi0, gbase, tid);
    __syncthreads();
    lvl_block<2, 1136>(bufB, bufA, f0, f1, psi0 + 1 * LS, gbase, tid);
    __syncthreads();
    lvl_block<4, 1116>(bufA, bufB, f0, f1, psi0 + 2 * LS, gbase, tid);
    __syncthreads();
    lvl_block<8, 1080>(bufB, bufA, f0, f1, psi0 + 3 * LS, gbase, tid);
    __syncthreads();
    lvl_poly<16, 1008, false>(bufA, bufB, f0, f1, psi0 + 4 * LS, nullptr, gbase, tid, false);
    __syncthreads();
    lvl_poly<32,  864, false>(bufB, bufA, f0, f1, psi0 + 5 * LS, nullptr, gbase, tid, false);
    __syncthreads();
    lvl_poly<64,  576, false>(bufA, bufB, f0, f1, psi0 + 6 * LS, nullptr, gbase, tid, false);
    __syncthreads();
    lvl_poly<128,   0, true >(bufB, bufA, f0, f1, psi0 + 7 * LS, yl_g, gbase, tid, wr_yl);
}

extern "C" void kernel_launch(void* const* d_in, const int* in_sizes, int n_in,
                              void* d_out, int out_size, void* d_ws, size_t ws_size,
                              hipStream_t stream)
{
    const float* x   = (const float*)d_in[0];
    const float* h0o = (const float*)d_in[1];
    const float* h1o = (const float*)d_in[2];
    const float* h0a = (const float*)d_in[3];
    const float* h1a = (const float*)d_in[4];
    const float* h0b = (const float*)d_in[5];
    const float* h1b = (const float*)d_in[6];

    const int nblocks = 64 * (T / TS);   // 1024
    udtcwt_fused<<<nblocks, NT, 0, stream>>>(x, h0o, h1o, h0a, h1a, h0b, h1b,
                                             (float*)d_out);
}

// Round 7
// 53.243 us; speedup vs baseline: 1.1982x; 1.1982x over previous
//
#include <hip/hip_runtime.h>

// UDTCWT split cascade.
// K1: levels 1-4 (D=1,2,4,8), halo 68, padded LDS, psi transposed through
//     the dead input LDS buffer -> all global stores coalesced float4.
//     phi4 -> __device__ g_phi4.
// K2: levels 5-8 (D=16..128), halo 1080, round-5 polyphase (stores already
//     coalesce for large D), staged from g_phi4.
// B=4, C=8 -> 16 chains, T=65536. Output: yl [4][8][T], yh [8][4][16][T].

static constexpr int B  = 4;
static constexpr int C2 = 16;
static constexpr int T  = 65536;
static constexpr int NT = 256;
static constexpr int TS = 4096;

// ---------------- K1 ----------------
static constexpr int HB1 = 68;
static constexpr int S1  = TS + 2 * HB1;     // 4232
static constexpr int SP1 = S1 + S1 / 32;     // 4364 padded floats

__device__ __forceinline__ int PH(int p) { return p + (p >> 5); }

__device__ float g_phi4[(size_t)B * C2 * T]; // 16.8 MB scratch (phi after lvl4)

// margins: lvl1 out 64; D=2 consumes 9 -> 54 (>=54 needed); D=4 -> 36; D=8 -> 0

template <int SH>
__device__ __forceinline__ void k1_lvl1(
    const float* __restrict__ in, float* __restrict__ out,
    const float* __restrict__ h0o, const float* __restrict__ h1o,
    float* __restrict__ psi_g, int gbase, int tid)
{
    float f0[5], f1[7];
#pragma unroll
    for (int k = 0; k < 5; ++k) f0[k] = h0o[k];
#pragma unroll
    for (int k = 0; k < 7; ++k) f1[k] = h1o[k];

    constexpr int WO    = SH ? -3 : -2;   // window origin vs output pos
    constexpr int FS    = SH ? 2 : 0;     // phi tap shift inside window
    constexpr int MO    = 64;
    constexpr int START = HB1 - MO;       // 4
    constexpr int END   = HB1 + TS + MO;  // 4228

    for (int p4 = START + tid * 4; p4 < END; p4 += NT * 4) {
        float w[10];
#pragma unroll
        for (int k = 0; k < 10; ++k) w[k] = in[PH(p4 + WO + k)];
        float a[4];
#pragma unroll
        for (int i = 0; i < 4; ++i) {
            float s = 0.f;
#pragma unroll
            for (int k = 0; k < 5; ++k) s += w[i + k + FS] * f0[k];
            a[i] = s;
        }
        if ((unsigned)(p4 - HB1) < (unsigned)TS) {
            float bb[4];
#pragma unroll
            for (int i = 0; i < 4; ++i) {
                float s = 0.f;
#pragma unroll
                for (int k = 0; k < 7; ++k) s += w[i + k] * f1[k];
                bb[i] = s;
            }
            *(float4*)&psi_g[gbase + p4] = make_float4(bb[0], bb[1], bb[2], bb[3]);
        }
        const bool inT = (unsigned)(gbase + p4) < (unsigned)T; // quad in or out
#pragma unroll
        for (int i = 0; i < 4; ++i) out[PH(p4 + i)] = inT ? a[i] : 0.f;
    }
}

// One dilated level: compute | bar | {phi->out, psi->in(stage)} | bar.
// Single chunk per thread (G<=NT) so staging into `in` is WAR-safe.
template <int D, int W, int MO>
__device__ __forceinline__ void k1_level(
    float* __restrict__ in, float* __restrict__ out,
    const float (&f0)[10], const float (&f1)[10],
    int gbase, int tid)
{
    constexpr int HALF  = 9 * D / 2;
    constexpr int START = HB1 - MO;
    constexpr int N     = TS + 2 * MO;
    static_assert(N % D == 0, "");
    constexpr int NPD   = N / D;
    constexpr int CPC   = (NPD + W - 1) / W;
    constexpr int G     = D * CPC;
    static_assert(G <= NT, "single chunk per thread required");
    constexpr int LOG2D = (D == 2 ? 1 : D == 4 ? 2 : 3);

    float a[W], bb[W];
    int p0 = 0;
    const bool act = tid < G;
    if (act) {
        int r  = tid & (D - 1);
        int q  = tid >> LOG2D;
        int ms = q * W;
        if (ms > NPD - W) ms = NPD - W;   // clamp (dup writes same values)
        p0 = START + r + ms * D;

        float v[W + 9];
#pragma unroll
        for (int n = 0; n < W + 9; ++n) v[n] = in[PH(p0 - HALF + n * D)];
#pragma unroll
        for (int m = 0; m < W; ++m) { a[m] = 0.f; bb[m] = 0.f; }
#pragma unroll
        for (int k = 0; k < 10; ++k)
#pragma unroll
            for (int m = 0; m < W; ++m) {
                float x = v[m + k];
                a[m] += x * f0[k]; bb[m] += x * f1[k];
            }
    }
    __syncthreads();
    if (act) {
#pragma unroll
        for (int m = 0; m < W; ++m) {
            int p = p0 + m * D;
            out[PH(p)] = ((unsigned)(gbase + p) < (unsigned)T) ? a[m] : 0.f;
            in[PH(p)]  = bb[m];           // stage psi into dead input buffer
        }
    }
    __syncthreads();
}

// Coalesced copy of the staged core range -> global (overlaps next compute).
__device__ __forceinline__ void k1_copyout(
    const float* __restrict__ buf, float* __restrict__ dst, int tid)
{
    for (int i4 = tid * 4; i4 < TS; i4 += NT * 4) {
        int ph = PH(HB1 + i4);            // quad contiguous (pads at 32-bnds)
        *(float4*)&dst[i4] = make_float4(buf[ph], buf[ph+1], buf[ph+2], buf[ph+3]);
    }
}

__global__ __launch_bounds__(256, 4) void udtcwt_k1(
    const float* __restrict__ x,
    const float* __restrict__ h0o, const float* __restrict__ h1o,
    const float* __restrict__ h0a, const float* __restrict__ h1a,
    const float* __restrict__ h0b, const float* __restrict__ h1b,
    float* __restrict__ out)
{
    __shared__ float A[SP1];
    __shared__ float Bf[SP1];

    const int tid   = threadIdx.x;
    const int bid   = blockIdx.x;
    const int tile  = bid & 15;
    const int chain = bid >> 4;
    const int shbit = chain & 1;
    const int cx    = (chain >> 1) & 7;
    const int b     = chain >> 4;
    const int c2    = shbit * 8 + cx;
    const int t0    = tile * TS;
    const int gbase = t0 - HB1;          // %4 == 0

    const float* xin = x + (size_t)(b * 8 + cx) * T;
    for (int i4 = tid * 4; i4 < S1; i4 += NT * 4) {
        int gg = gbase + i4;             // quad fully in or out of [0,T)
        float4 v = ((unsigned)gg < (unsigned)T)
                 ? *(const float4*)&xin[gg]
                 : make_float4(0.f, 0.f, 0.f, 0.f);
        int ph = PH(i4);
        A[ph] = v.x; A[ph+1] = v.y; A[ph+2] = v.z; A[ph+3] = v.w;
    }

    float f0[10], f1[10];
    {
        const float* F0 = (c2 & 1) ? h0b : h0a;
        const float* F1 = (c2 & 1) ? h1b : h1a;
#pragma unroll
        for (int k = 0; k < 10; ++k) { f0[k] = F0[k]; f1[k] = F1[k]; }
    }

    float* yh   = out + (size_t)B * 8 * T;
    const size_t LS = (size_t)B * C2 * T;
    float* psi0 = yh + (size_t)(b * C2 + c2) * T;

    __syncthreads();
    if (shbit) k1_lvl1<1>(A, Bf, h0o, h1o, psi0, gbase, tid);
    else       k1_lvl1<0>(A, Bf, h0o, h1o, psi0, gbase, tid);
    __syncthreads();

    k1_level<2, 17, 54>(Bf, A, f0, f1, gbase, tid);
    k1_copyout(Bf, psi0 + 1 * LS + t0, tid);
    k1_level<4, 17, 36>(A, Bf, f0, f1, gbase, tid);
    k1_copyout(A, psi0 + 2 * LS + t0, tid);
    k1_level<8, 16, 0>(Bf, A, f0, f1, gbase, tid);
    k1_copyout(Bf, psi0 + 3 * LS + t0, tid);
    k1_copyout(A, g_phi4 + (size_t)(b * C2 + c2) * T + t0, tid);
}

// ---------------- K2: levels 5-8 (round-5 polyphase, unpadded) ----------------
static constexpr int HB2 = 1080;
static constexpr int S2  = TS + 2 * HB2;     // 6256

template <int D, int MO, bool LAST>
__device__ __forceinline__ void k2_poly(
    const float* __restrict__ in, float* __restrict__ out,
    const float (&f0)[10], const float (&f1)[10],
    float* __restrict__ psi_g, float* __restrict__ yl_g,
    int gbase, int tid, bool wr_yl)
{
    constexpr int W     = 9;
    constexpr int HALF  = 9 * D / 2;
    constexpr int START = HB2 - MO;
    constexpr int END   = HB2 + TS + MO;
    constexpr int N     = END - START;
    static_assert(N % D == 0, "");
    constexpr int NPD   = N / D;
    constexpr int CPC   = (NPD + W - 1) / W;
    constexpr int G     = D * CPC;
    constexpr int LOG2D = (D == 16 ? 4 : D == 32 ? 5 : D == 64 ? 6 : 7);

    for (int g = tid; g < G; g += NT) {
        int r = g & (D - 1);
        int q = g >> LOG2D;
        int ms = q * W;
        if (ms > NPD - W) ms = NPD - W;
        int p0 = START + r + ms * D;

        float v[W + 9];
#pragma unroll
        for (int n = 0; n < W + 9; ++n) v[n] = in[p0 - HALF + n * D];

        if constexpr (!LAST) {
            const bool anyc = (p0 + (W - 1) * D >= HB2) && (p0 < HB2 + TS);
            float a[W], bb[W];
            if (anyc) {
#pragma unroll
                for (int m = 0; m < W; ++m) { a[m] = 0.f; bb[m] = 0.f; }
#pragma unroll
                for (int k = 0; k < 10; ++k)
#pragma unroll
                    for (int m = 0; m < W; ++m) {
                        float xx = v[m + k];
                        a[m] += xx * f0[k]; bb[m] += xx * f1[k];
                    }
#pragma unroll
                for (int m = 0; m < W; ++m) {
                    int p = p0 + m * D;
                    if ((unsigned)(p - HB2) < (unsigned)TS)
                        psi_g[gbase + p] = bb[m];
                }
            } else {
#pragma unroll
                for (int m = 0; m < W; ++m) a[m] = 0.f;
#pragma unroll
                for (int k = 0; k < 10; ++k)
#pragma unroll
                    for (int m = 0; m < W; ++m) a[m] += v[m + k] * f0[k];
            }
#pragma unroll
            for (int m = 0; m < W; ++m) {
                int p = p0 + m * D;
                out[p] = ((unsigned)(gbase + p) < (unsigned)T) ? a[m] : 0.f;
            }
        } else {
            float bb[W];
#pragma unroll
            for (int m = 0; m < W; ++m) bb[m] = 0.f;
#pragma unroll
            for (int k = 0; k < 10; ++k)
#pragma unroll
                for (int m = 0; m < W; ++m) bb[m] += v[m + k] * f1[k];
#pragma unroll
            for (int m = 0; m < W; ++m) psi_g[gbase + p0 + m * D] = bb[m];
            if (wr_yl) {
                float a[W];
#pragma unroll
                for (int m = 0; m < W; ++m) a[m] = 0.f;
#pragma unroll
                for (int k = 0; k < 10; ++k)
#pragma unroll
                    for (int m = 0; m < W; ++m) a[m] += v[m + k] * f0[k];
#pragma unroll
                for (int m = 0; m < W; ++m) yl_g[gbase + p0 + m * D] = a[m];
            }
        }
    }
}

__global__ __launch_bounds__(256, 3) void udtcwt_k2(
    const float* __restrict__ h0a, const float* __restrict__ h1a,
    const float* __restrict__ h0b, const float* __restrict__ h1b,
    float* __restrict__ out)
{
    __shared__ float A[S2];
    __shared__ float Bf[S2];

    const int tid   = threadIdx.x;
    const int bid   = blockIdx.x;
    const int tile  = bid & 15;
    const int chain = bid >> 4;
    const int shbit = chain & 1;
    const int cx    = (chain >> 1) & 7;
    const int b     = chain >> 4;
    const int c2    = shbit * 8 + cx;
    const int gbase = tile * TS - HB2;   // %4 == 0

    const float* pin = g_phi4 + (size_t)(b * C2 + c2) * T;
    for (int i4 = tid * 4; i4 < S2; i4 += NT * 4) {
        int gg = gbase + i4;
        float4 v = ((unsigned)gg < (unsigned)T)
                 ? *(const float4*)&pin[gg]
                 : make_float4(0.f, 0.f, 0.f, 0.f);
        *(float4*)&A[i4] = v;
    }

    float f0[10], f1[10];
    {
        const float* F0 = (c2 & 1) ? h0b : h0a;
        const float* F1 = (c2 & 1) ? h1b : h1a;
#pragma unroll
        for (int k = 0; k < 10; ++k) { f0[k] = F0[k]; f1[k] = F1[k]; }
    }

    float* yl_g = out + (size_t)(b * 8 + c2) * T;    // used when c2<8
    float* yh   = out + (size_t)B * 8 * T;
    const size_t LS = (size_t)B * C2 * T;
    float* psi0 = yh + (size_t)(b * C2 + c2) * T;
    const bool wr_yl = (c2 < 8);

    __syncthreads();
    k2_poly<16, 1008, false>(A, Bf, f0, f1, psi0 + 4 * LS, nullptr, gbase, tid, false);
    __syncthreads();
    k2_poly<32,  864, false>(Bf, A, f0, f1, psi0 + 5 * LS, nullptr, gbase, tid, false);
    __syncthreads();
    k2_poly<64,  576, false>(A, Bf, f0, f1, psi0 + 6 * LS, nullptr, gbase, tid, false);
    __syncthreads();
    k2_poly<128,   0, true >(Bf, A, f0, f1, psi0 + 7 * LS, yl_g, gbase, tid, wr_yl);
}

extern "C" void kernel_launch(void* const* d_in, const int* in_sizes, int n_in,
                              void* d_out, int out_size, void* d_ws, size_t ws_size,
                              hipStream_t stream)
{
    const float* x   = (const float*)d_in[0];
    const float* h0o = (const float*)d_in[1];
    const float* h1o = (const float*)d_in[2];
    const float* h0a = (const float*)d_in[3];
    const float* h1a = (const float*)d_in[4];
    const float* h0b = (const float*)d_in[5];
    const float* h1b = (const float*)d_in[6];

    const int nblocks = 64 * (T / TS);   // 1024
    udtcwt_k1<<<nblocks, NT, 0, stream>>>(x, h0o, h1o, h0a, h1a, h0b, h1b,
                                          (float*)d_out);
    udtcwt_k2<<<nblocks, NT, 0, stream>>>(h0a, h1a, h0b, h1b, (float*)d_out);
}

// Round 8
// 50.389 us; speedup vs baseline: 1.2660x; 1.0566x over previous
//
#include <hip/hip_runtime.h>

// UDTCWT split cascade, occupancy edition.
// K1: levels 1-4 (D=1,2,4,8), TS=2048, halo 68, padded LDS, psi transposed
//     through dead LDS buffer -> coalesced float4 stores. phi4 -> g_phi4.
// K2: levels 5-8 (D=16..128), TS=4096, NT=512, polyphase W=9.
// Filters hoisted to SGPRs via readfirstlane (cuts VGPR -> more blocks/CU).
// B=4, C=8 -> 16 chains, T=65536. Output: yl [4][8][T], yh [8][4][16][T].

static constexpr int B  = 4;
static constexpr int C2 = 16;
static constexpr int T  = 65536;

__device__ __forceinline__ float rfl(float x) {
    return __int_as_float(__builtin_amdgcn_readfirstlane(__float_as_int(x)));
}

__device__ __forceinline__ int PH(int p) { return p + (p >> 5); }

__device__ float g_phi4[(size_t)B * C2 * T]; // 16.8 MB phi-after-lvl4

// ---------------- K1 ----------------
static constexpr int NT1 = 256;
static constexpr int TS1 = 2048;
static constexpr int HB1 = 68;
static constexpr int S1  = TS1 + 2 * HB1;    // 2184
static constexpr int SP1 = S1 + S1 / 32;     // padded

// margins: lvl1 out 64; lvl2(D2) out 54; lvl3(D4) out 36; lvl4(D8) out 0.

template <int SH>
__device__ __forceinline__ void k1_lvl1(
    const float* __restrict__ in, float* __restrict__ out,
    const float* __restrict__ h0o, const float* __restrict__ h1o,
    float* __restrict__ psi_g, int gbase, int tid)
{
    float f0[5], f1[7];
#pragma unroll
    for (int k = 0; k < 5; ++k) f0[k] = rfl(h0o[k]);
#pragma unroll
    for (int k = 0; k < 7; ++k) f1[k] = rfl(h1o[k]);

    constexpr int WO    = SH ? -3 : -2;
    constexpr int FS    = SH ? 2 : 0;
    constexpr int MO    = 64;
    constexpr int START = HB1 - MO;        // 4
    constexpr int END   = HB1 + TS1 + MO;  // 2180

    for (int p4 = START + tid * 4; p4 < END; p4 += NT1 * 4) {
        float w[10];
#pragma unroll
        for (int k = 0; k < 10; ++k) w[k] = in[PH(p4 + WO + k)];
        float a[4];
#pragma unroll
        for (int i = 0; i < 4; ++i) {
            float s = 0.f;
#pragma unroll
            for (int k = 0; k < 5; ++k) s += w[i + k + FS] * f0[k];
            a[i] = s;
        }
        if ((unsigned)(p4 - HB1) < (unsigned)TS1) {
            float bb[4];
#pragma unroll
            for (int i = 0; i < 4; ++i) {
                float s = 0.f;
#pragma unroll
                for (int k = 0; k < 7; ++k) s += w[i + k] * f1[k];
                bb[i] = s;
            }
            *(float4*)&psi_g[gbase + p4] = make_float4(bb[0], bb[1], bb[2], bb[3]);
        }
        const bool inT = (unsigned)(gbase + p4) < (unsigned)T;
#pragma unroll
        for (int i = 0; i < 4; ++i) out[PH(p4 + i)] = inT ? a[i] : 0.f;
    }
}

// compute | bar | {phi->out, psi->in(stage)} | bar.  G<=NT1 single chunk.
template <int D, int W, int MO>
__device__ __forceinline__ void k1_level(
    float* __restrict__ in, float* __restrict__ out,
    const float (&f0)[10], const float (&f1)[10],
    int gbase, int tid)
{
    constexpr int HALF  = 9 * D / 2;
    constexpr int START = HB1 - MO;
    constexpr int N     = TS1 + 2 * MO;
    static_assert(N % D == 0, "");
    constexpr int NPD   = N / D;
    constexpr int CPC   = (NPD + W - 1) / W;
    constexpr int G     = D * CPC;
    static_assert(G <= NT1, "single chunk per thread required");
    constexpr int LOG2D = (D == 2 ? 1 : D == 4 ? 2 : 3);

    float a[W], bb[W];
    int p0 = 0;
    const bool act = tid < G;
    if (act) {
        int r  = tid & (D - 1);
        int q  = tid >> LOG2D;
        int ms = q * W;
        if (ms > NPD - W) ms = NPD - W;   // clamp (dup work, benign)
        p0 = START + r + ms * D;

        float v[W + 9];
#pragma unroll
        for (int n = 0; n < W + 9; ++n) v[n] = in[PH(p0 - HALF + n * D)];
#pragma unroll
        for (int m = 0; m < W; ++m) { a[m] = 0.f; bb[m] = 0.f; }
#pragma unroll
        for (int k = 0; k < 10; ++k)
#pragma unroll
            for (int m = 0; m < W; ++m) {
                float x = v[m + k];
                a[m] += x * f0[k]; bb[m] += x * f1[k];
            }
    }
    __syncthreads();
    if (act) {
#pragma unroll
        for (int m = 0; m < W; ++m) {
            int p = p0 + m * D;
            out[PH(p)] = ((unsigned)(gbase + p) < (unsigned)T) ? a[m] : 0.f;
            in[PH(p)]  = bb[m];
        }
    }
    __syncthreads();
}

__device__ __forceinline__ void k1_copyout(
    const float* __restrict__ buf, float* __restrict__ dst, int tid)
{
    for (int i4 = tid * 4; i4 < TS1; i4 += NT1 * 4) {
        int ph = PH(HB1 + i4);
        *(float4*)&dst[i4] = make_float4(buf[ph], buf[ph+1], buf[ph+2], buf[ph+3]);
    }
}

__global__ __launch_bounds__(256, 6) void udtcwt_k1(
    const float* __restrict__ x,
    const float* __restrict__ h0o, const float* __restrict__ h1o,
    const float* __restrict__ h0a, const float* __restrict__ h1a,
    const float* __restrict__ h0b, const float* __restrict__ h1b,
    float* __restrict__ out)
{
    __shared__ float A[SP1];
    __shared__ float Bf[SP1];

    const int tid   = threadIdx.x;
    const int bid   = blockIdx.x;
    const int tile  = bid & 31;          // 32 tiles of 2048
    const int chain = bid >> 5;          // 0..63
    const int shbit = chain & 1;
    const int cx    = (chain >> 1) & 7;
    const int b     = chain >> 4;
    const int c2    = shbit * 8 + cx;
    const int t0    = tile * TS1;
    const int gbase = t0 - HB1;          // %4 == 0

    const float* xin = x + (size_t)(b * 8 + cx) * T;
    for (int i4 = tid * 4; i4 < S1; i4 += NT1 * 4) {
        int gg = gbase + i4;
        float4 v = ((unsigned)gg < (unsigned)T)
                 ? *(const float4*)&xin[gg]
                 : make_float4(0.f, 0.f, 0.f, 0.f);
        int ph = PH(i4);
        A[ph] = v.x; A[ph+1] = v.y; A[ph+2] = v.z; A[ph+3] = v.w;
    }

    float f0[10], f1[10];
    {
        const float* F0 = (c2 & 1) ? h0b : h0a;
        const float* F1 = (c2 & 1) ? h1b : h1a;
#pragma unroll
        for (int k = 0; k < 10; ++k) { f0[k] = rfl(F0[k]); f1[k] = rfl(F1[k]); }
    }

    float* yh   = out + (size_t)B * 8 * T;
    const size_t LS = (size_t)B * C2 * T;
    float* psi0 = yh + (size_t)(b * C2 + c2) * T;

    __syncthreads();
    if (shbit) k1_lvl1<1>(A, Bf, h0o, h1o, psi0, gbase, tid);
    else       k1_lvl1<0>(A, Bf, h0o, h1o, psi0, gbase, tid);
    __syncthreads();

    k1_level<2, 9, 54>(Bf, A, f0, f1, gbase, tid);
    k1_copyout(Bf, psi0 + 1 * LS + t0, tid);
    k1_level<4, 9, 36>(A, Bf, f0, f1, gbase, tid);
    k1_copyout(A, psi0 + 2 * LS + t0, tid);
    k1_level<8, 9, 0>(Bf, A, f0, f1, gbase, tid);
    k1_copyout(Bf, psi0 + 3 * LS + t0, tid);
    k1_copyout(A, g_phi4 + (size_t)(b * C2 + c2) * T + t0, tid);
}

// ---------------- K2: levels 5-8, NT=512 ----------------
static constexpr int NT2 = 512;
static constexpr int TS2 = 4096;
static constexpr int HB2 = 1080;
static constexpr int S2  = TS2 + 2 * HB2;    // 6256

template <int D, int MO, bool LAST>
__device__ __forceinline__ void k2_poly(
    const float* __restrict__ in, float* __restrict__ out,
    const float (&f0)[10], const float (&f1)[10],
    float* __restrict__ psi_g, float* __restrict__ yl_g,
    int gbase, int tid, bool wr_yl)
{
    constexpr int W     = 9;
    constexpr int HALF  = 9 * D / 2;
    constexpr int START = HB2 - MO;
    constexpr int END   = HB2 + TS2 + MO;
    constexpr int N     = END - START;
    static_assert(N % D == 0, "");
    constexpr int NPD   = N / D;
    constexpr int CPC   = (NPD + W - 1) / W;
    constexpr int G     = D * CPC;
    constexpr int LOG2D = (D == 16 ? 4 : D == 32 ? 5 : D == 64 ? 6 : 7);

    for (int g = tid; g < G; g += NT2) {
        int r = g & (D - 1);
        int q = g >> LOG2D;
        int ms = q * W;
        if (ms > NPD - W) ms = NPD - W;
        int p0 = START + r + ms * D;

        float v[W + 9];
#pragma unroll
        for (int n = 0; n < W + 9; ++n) v[n] = in[p0 - HALF + n * D];

        if constexpr (!LAST) {
            const bool anyc = (p0 + (W - 1) * D >= HB2) && (p0 < HB2 + TS2);
            float a[W], bb[W];
            if (anyc) {
#pragma unroll
                for (int m = 0; m < W; ++m) { a[m] = 0.f; bb[m] = 0.f; }
#pragma unroll
                for (int k = 0; k < 10; ++k)
#pragma unroll
                    for (int m = 0; m < W; ++m) {
                        float xx = v[m + k];
                        a[m] += xx * f0[k]; bb[m] += xx * f1[k];
                    }
#pragma unroll
                for (int m = 0; m < W; ++m) {
                    int p = p0 + m * D;
                    if ((unsigned)(p - HB2) < (unsigned)TS2)
                        psi_g[gbase + p] = bb[m];
                }
            } else {
#pragma unroll
                for (int m = 0; m < W; ++m) a[m] = 0.f;
#pragma unroll
                for (int k = 0; k < 10; ++k)
#pragma unroll
                    for (int m = 0; m < W; ++m) a[m] += v[m + k] * f0[k];
            }
#pragma unroll
            for (int m = 0; m < W; ++m) {
                int p = p0 + m * D;
                out[p] = ((unsigned)(gbase + p) < (unsigned)T) ? a[m] : 0.f;
            }
        } else {
            float bb[W];
#pragma unroll
            for (int m = 0; m < W; ++m) bb[m] = 0.f;
#pragma unroll
            for (int k = 0; k < 10; ++k)
#pragma unroll
                for (int m = 0; m < W; ++m) bb[m] += v[m + k] * f1[k];
#pragma unroll
            for (int m = 0; m < W; ++m) psi_g[gbase + p0 + m * D] = bb[m];
            if (wr_yl) {
                float a[W];
#pragma unroll
                for (int m = 0; m < W; ++m) a[m] = 0.f;
#pragma unroll
                for (int k = 0; k < 10; ++k)
#pragma unroll
                    for (int m = 0; m < W; ++m) a[m] += v[m + k] * f0[k];
#pragma unroll
                for (int m = 0; m < W; ++m) yl_g[gbase + p0 + m * D] = a[m];
            }
        }
    }
}

__global__ __launch_bounds__(512, 6) void udtcwt_k2(
    const float* __restrict__ h0a, const float* __restrict__ h1a,
    const float* __restrict__ h0b, const float* __restrict__ h1b,
    float* __restrict__ out)
{
    __shared__ float A[S2];
    __shared__ float Bf[S2];

    const int tid   = threadIdx.x;
    const int bid   = blockIdx.x;
    const int tile  = bid & 15;          // 16 tiles of 4096
    const int chain = bid >> 4;
    const int shbit = chain & 1;
    const int cx    = (chain >> 1) & 7;
    const int b     = chain >> 4;
    const int c2    = shbit * 8 + cx;
    const int gbase = tile * TS2 - HB2;  // %4 == 0

    const float* pin = g_phi4 + (size_t)(b * C2 + c2) * T;
    for (int i4 = tid * 4; i4 < S2; i4 += NT2 * 4) {
        int gg = gbase + i4;
        float4 v = ((unsigned)gg < (unsigned)T)
                 ? *(const float4*)&pin[gg]
                 : make_float4(0.f, 0.f, 0.f, 0.f);
        *(float4*)&A[i4] = v;
    }

    float f0[10], f1[10];
    {
        const float* F0 = (c2 & 1) ? h0b : h0a;
        const float* F1 = (c2 & 1) ? h1b : h1a;
#pragma unroll
        for (int k = 0; k < 10; ++k) { f0[k] = rfl(F0[k]); f1[k] = rfl(F1[k]); }
    }

    float* yl_g = out + (size_t)(b * 8 + c2) * T;    // used when c2<8
    float* yh   = out + (size_t)B * 8 * T;
    const size_t LS = (size_t)B * C2 * T;
    float* psi0 = yh + (size_t)(b * C2 + c2) * T;
    const bool wr_yl = (c2 < 8);

    __syncthreads();
    k2_poly<16, 1008, false>(A, Bf, f0, f1, psi0 + 4 * LS, nullptr, gbase, tid, false);
    __syncthreads();
    k2_poly<32,  864, false>(Bf, A, f0, f1, psi0 + 5 * LS, nullptr, gbase, tid, false);
    __syncthreads();
    k2_poly<64,  576, false>(A, Bf, f0, f1, psi0 + 6 * LS, nullptr, gbase, tid, false);
    __syncthreads();
    k2_poly<128,   0, true >(Bf, A, f0, f1, psi0 + 7 * LS, yl_g, gbase, tid, wr_yl);
}

extern "C" void kernel_launch(void* const* d_in, const int* in_sizes, int n_in,
                              void* d_out, int out_size, void* d_ws, size_t ws_size,
                              hipStream_t stream)
{
    const float* x   = (const float*)d_in[0];
    const float* h0o = (const float*)d_in[1];
    const float* h1o = (const float*)d_in[2];
    const float* h0a = (const float*)d_in[3];
    const float* h1a = (const float*)d_in[4];
    const float* h0b = (const float*)d_in[5];
    const float* h1b = (const float*)d_in[6];

    udtcwt_k1<<<64 * (T / TS1), NT1, 0, stream>>>(x, h0o, h1o, h0a, h1a, h0b, h1b,
                                                  (float*)d_out);
    udtcwt_k2<<<64 * (T / TS2), NT2, 0, stream>>>(h0a, h1a, h0b, h1b,
                                                  (float*)d_out);
}